// Round 1
// baseline (1338.239 us; speedup 1.0000x reference)
//
#include <hip/hip_runtime.h>
#include <hip/hip_bf16.h>

typedef __bf16 bf16x8 __attribute__((ext_vector_type(8)));
typedef float f32x4 __attribute__((ext_vector_type(4)));

#define MFMA16(a, b, c) __builtin_amdgcn_mfma_f32_16x16x32_bf16(a, b, c, 0, 0, 0)

#define T_SEQ 2048
#define D_MODEL 1024
#define N_HEADS 16
#define HEAD_DIM 64
#define D_FF 4096
#define QKV_STRIDE 3072

__device__ __forceinline__ float sigm(float x) { return 1.f / (1.f + __expf(-x)); }

// ---------------- fp32 -> bf16 cast, 8 elements/thread ----------------
__global__ __launch_bounds__(256) void cast_bf16_kernel(
    const float* __restrict__ in, __bf16* __restrict__ out, int n8)
{
    int i = blockIdx.x * blockDim.x + threadIdx.x;
    if (i >= n8) return;
    const float4* p = (const float4*)in + (size_t)i * 2;
    float4 a = p[0], b = p[1];
    union { __bf16 h[8]; float4 v; } u;
    u.h[0] = (__bf16)a.x; u.h[1] = (__bf16)a.y; u.h[2] = (__bf16)a.z; u.h[3] = (__bf16)a.w;
    u.h[4] = (__bf16)b.x; u.h[5] = (__bf16)b.y; u.h[6] = (__bf16)b.z; u.h[7] = (__bf16)b.w;
    ((float4*)out)[i] = u.v;
}

// ---------------- LayerNorm: fp32 in -> bf16 out ----------------
__global__ __launch_bounds__(256) void ln_kernel(
    const float* __restrict__ x, const float* __restrict__ g,
    const float* __restrict__ b, __bf16* __restrict__ out)
{
    const int t = blockIdx.x;
    const int tid = threadIdx.x;
    float4 xv = *(const float4*)&x[t * D_MODEL + tid * 4];
    float s = xv.x + xv.y + xv.z + xv.w;
    float ss = xv.x * xv.x + xv.y * xv.y + xv.z * xv.z + xv.w * xv.w;
    for (int off = 1; off < 64; off <<= 1) {
        s += __shfl_xor(s, off);
        ss += __shfl_xor(ss, off);
    }
    __shared__ float sb[8];
    int w = tid >> 6, lane = tid & 63;
    if (lane == 0) { sb[w] = s; sb[4 + w] = ss; }
    __syncthreads();
    s = sb[0] + sb[1] + sb[2] + sb[3];
    ss = sb[4] + sb[5] + sb[6] + sb[7];
    float mu = s * (1.f / D_MODEL);
    float var = ss * (1.f / D_MODEL) - mu * mu;
    float rs = rsqrtf(var + 1e-5f);
    const float* xp = (const float*)&xv;
    for (int i = 0; i < 4; ++i) {
        int d = tid * 4 + i;
        out[t * D_MODEL + d] = (__bf16)((xp[i] - mu) * rs * g[d] + b[d]);
    }
}

// ---------------- NT GEMM: C[m][n] = sum_k A[m][k]*B[n][k] (+epilogue) -----
// EPI 0: bf16 out (+opt bias); EPI 1: bias + exact GELU -> bf16; EPI 2: fp32 out = resid + C (+opt bias)
template<int EPI>
__global__ __launch_bounds__(256) void gemm_nt(
    const __bf16* __restrict__ A, const __bf16* __restrict__ B,
    const float* __restrict__ bias, const float* __restrict__ resid,
    __bf16* __restrict__ outb, float* __restrict__ outf,
    int M, int N, int K)
{
    __shared__ __bf16 As[128 * 40];
    __shared__ __bf16 Bs[128 * 40];
    const int tid = threadIdx.x;
    const int lane = tid & 63, w = tid >> 6;
    const int quad = lane >> 4, l16 = lane & 15;
    const int bm = blockIdx.x * 128, bn = blockIdx.y * 128;
    const int wm = (w & 1) * 64, wn = (w >> 1) * 64;
    f32x4 acc[4][4] = {};

    for (int k0 = 0; k0 < K; k0 += 32) {
        __syncthreads();
        for (int i = 0; i < 2; ++i) {
            int c = tid + 256 * i;
            int row = c >> 2, col = (c & 3) << 3;
            *(float4*)&As[row * 40 + col] = *(const float4*)&A[(size_t)(bm + row) * K + k0 + col];
            *(float4*)&Bs[row * 40 + col] = *(const float4*)&B[(size_t)(bn + row) * K + k0 + col];
        }
        __syncthreads();
        bf16x8 af[4], bfr[4];
        for (int i = 0; i < 4; ++i)
            af[i] = *(const bf16x8*)&As[(wm + i * 16 + l16) * 40 + quad * 8];
        for (int j = 0; j < 4; ++j)
            bfr[j] = *(const bf16x8*)&Bs[(wn + j * 16 + l16) * 40 + quad * 8];
        for (int i = 0; i < 4; ++i)
            for (int j = 0; j < 4; ++j)
                acc[i][j] = MFMA16(af[i], bfr[j], acc[i][j]);
    }

    for (int i = 0; i < 4; ++i) {
        for (int j = 0; j < 4; ++j) {
            for (int r = 0; r < 4; ++r) {
                int row = bm + wm + i * 16 + quad * 4 + r;
                int col = bn + wn + j * 16 + l16;
                float v = acc[i][j][r];
                if (bias) v += bias[col];
                if (EPI == 1) v = 0.5f * v * (1.f + erff(v * 0.70710678118f));
                if (EPI == 2) outf[(size_t)row * N + col] = resid[(size_t)row * N + col] + v;
                else          outb[(size_t)row * N + col] = (__bf16)v;
            }
        }
    }
}

// ---------------- fused dual-variant flash attention ----------------
// block = (q-tile 64 rows, head); 4 waves, each wave 16 q-rows.
// Outputs merged directly into cat[t][0:1024] (txt) and cat[t][1024:2048] (cau).
__global__ __launch_bounds__(256) void attn_kernel(
    const __bf16* __restrict__ qkv, const float* __restrict__ lmask,
    __bf16* __restrict__ cat)
{
    __shared__ __bf16 Ks[32 * 80];     // [s][dh], stride 80
    __shared__ __bf16 Vt[64 * 48];     // [dh][s], stride 48
    __shared__ __bf16 Pw[4][16 * 48];  // per-wave P round-trip, stride 48

    const int tid = threadIdx.x;
    const int w = tid >> 6, lane = tid & 63;
    const int quad = lane >> 4, l16 = lane & 15;
    const int qt = blockIdx.x, h = blockIdx.y;
    const int q0 = qt * 64;

    // Q fragments (A-operand layout): row = l16 (within wave's 16 rows), k = quad*8+j
    const int tq = q0 + w * 16 + l16;
    bf16x8 qf[2];
    qf[0] = *(const bf16x8*)&qkv[(size_t)tq * QKV_STRIDE + h * 64 + quad * 8];
    qf[1] = *(const bf16x8*)&qkv[(size_t)tq * QKV_STRIDE + h * 64 + 32 + quad * 8];

    float m_[2][4], l_[2][4];
    f32x4 O[2][4] = {};
    for (int v = 0; v < 2; ++v)
        for (int r = 0; r < 4; ++r) { m_[v][r] = -1e30f; l_[v][r] = 0.f; }

    const int trow[1] = {0}; (void)trow;

    for (int s0 = 0; s0 < q0 + 64; s0 += 32) {
        __syncthreads();
        {
            int row = tid >> 3, c8 = (tid & 7) << 3;
            *(float4*)&Ks[row * 80 + c8] =
                *(const float4*)&qkv[(size_t)(s0 + row) * QKV_STRIDE + 1024 + h * 64 + c8];
            float4 vv = *(const float4*)&qkv[(size_t)(s0 + row) * QKV_STRIDE + 2048 + h * 64 + c8];
            const __bf16* vp = (const __bf16*)&vv;
            for (int j = 0; j < 8; ++j) Vt[(c8 + j) * 48 + row] = vp[j];
        }
        __syncthreads();

        // scores S[c]: 16 q-rows x 16 s-cols, c in {0,1}  (C-layout: row=quad*4+r, col=l16)
        f32x4 S[2];
        for (int c = 0; c < 2; ++c) {
            bf16x8 kf0 = *(const bf16x8*)&Ks[(c * 16 + l16) * 80 + quad * 8];
            bf16x8 kf1 = *(const bf16x8*)&Ks[(c * 16 + l16) * 80 + 32 + quad * 8];
            f32x4 z = {};
            z = MFMA16(qf[0], kf0, z);
            z = MFMA16(qf[1], kf1, z);
            S[c] = z * 0.125f;  // 1/sqrt(64)
        }

        // per-element sigmoid(log_mask) + causal mask flags
        float sig[2][4];
        bool msk[2][4];
        for (int c = 0; c < 2; ++c) {
            int sc = s0 + c * 16 + l16;
            for (int r = 0; r < 4; ++r) {
                int tr = q0 + w * 16 + quad * 4 + r;
                msk[c][r] = (sc > tr);
                sig[c][r] = sigm(lmask[((size_t)h * T_SEQ + tr) * T_SEQ + sc]);
            }
        }

        // V fragments (B-operand layout): n = l16 (dh within subtile), k = quad*8+j (s)
        bf16x8 vf[4];
        for (int j = 0; j < 4; ++j)
            vf[j] = *(const bf16x8*)&Vt[(j * 16 + l16) * 48 + quad * 8];

        for (int v = 0; v < 2; ++v) {
            float p0[4], p1[4], mx[4];
            for (int r = 0; r < 4; ++r) {
                float a = msk[0][r] ? -1e30f : (v ? S[0][r] * sig[0][r] : S[0][r]);
                float b = msk[1][r] ? -1e30f : (v ? S[1][r] * sig[1][r] : S[1][r]);
                p0[r] = a; p1[r] = b;
                mx[r] = fmaxf(a, b);
            }
            for (int r = 0; r < 4; ++r)
                for (int off = 1; off < 16; off <<= 1)
                    mx[r] = fmaxf(mx[r], __shfl_xor(mx[r], off));
            float al[4];
            for (int r = 0; r < 4; ++r) {
                float mn = fmaxf(m_[v][r], mx[r]);
                al[r] = __expf(m_[v][r] - mn);
                m_[v][r] = mn;
                p0[r] = __expf(p0[r] - mn);
                p1[r] = __expf(p1[r] - mn);
                float rs = p0[r] + p1[r];
                for (int off = 1; off < 16; off <<= 1) rs += __shfl_xor(rs, off);
                l_[v][r] = l_[v][r] * al[r] + rs;
            }
            for (int j = 0; j < 4; ++j)
                for (int r = 0; r < 4; ++r) O[v][j][r] *= al[r];
            // P: C-layout -> LDS -> A-layout
            for (int r = 0; r < 4; ++r) {
                Pw[w][(quad * 4 + r) * 48 + l16] = (__bf16)p0[r];
                Pw[w][(quad * 4 + r) * 48 + 16 + l16] = (__bf16)p1[r];
            }
            bf16x8 pf = *(const bf16x8*)&Pw[w][l16 * 48 + quad * 8];
            for (int j = 0; j < 4; ++j)
                O[v][j] = MFMA16(pf, vf[j], O[v][j]);
        }
    }

    for (int v = 0; v < 2; ++v)
        for (int j = 0; j < 4; ++j)
            for (int r = 0; r < 4; ++r) {
                int tr = q0 + w * 16 + quad * 4 + r;
                int col = v * 1024 + h * 64 + j * 16 + l16;
                cat[(size_t)tr * 2048 + col] = (__bf16)(O[v][j][r] / l_[v][r]);
            }
}

// ---------------- sparsity scalar: mean(sigmoid(log_mask)) ----------------
__global__ void zero_acc_kernel(float* acc) { acc[0] = 0.f; }

__global__ __launch_bounds__(256) void sigmean_kernel(
    const float* __restrict__ lm, float* __restrict__ acc)
{
    const size_t total = (size_t)N_HEADS * T_SEQ * T_SEQ;  // 67108864
    size_t idx = ((size_t)blockIdx.x * 256 + threadIdx.x) * 4;
    const size_t stride = (size_t)gridDim.x * 256 * 4;
    float s = 0.f;
    for (size_t i = idx; i < total; i += stride) {
        float4 a = *(const float4*)&lm[i];
        s += sigm(a.x) + sigm(a.y) + sigm(a.z) + sigm(a.w);
    }
    for (int off = 1; off < 64; off <<= 1) s += __shfl_xor(s, off);
    __shared__ float sb[4];
    int w = threadIdx.x >> 6;
    if ((threadIdx.x & 63) == 0) sb[w] = s;
    __syncthreads();
    if (threadIdx.x == 0) atomicAdd(acc, sb[0] + sb[1] + sb[2] + sb[3]);
}

__global__ void write_sp_kernel(const float* __restrict__ acc, float* __restrict__ out)
{
    out[(size_t)T_SEQ * D_MODEL] = 0.0005f * acc[0] * (1.f / 67108864.f);
}

// ---------------- launch ----------------
extern "C" void kernel_launch(void* const* d_in, const int* in_sizes, int n_in,
                              void* d_out, int out_size, void* d_ws, size_t ws_size,
                              hipStream_t stream)
{
    const float* x      = (const float*)d_in[0];
    const float* W_qkv  = (const float*)d_in[2];
    const float* W_out  = (const float*)d_in[3];
    const float* lmask  = (const float*)d_in[4];
    const float* W_gate = (const float*)d_in[5];
    const float* b_gate = (const float*)d_in[6];
    const float* g1     = (const float*)d_in[7];
    const float* b1     = (const float*)d_in[8];
    const float* g2     = (const float*)d_in[9];
    const float* b2     = (const float*)d_in[10];
    const float* W_ff1  = (const float*)d_in[11];
    const float* b_ff1  = (const float*)d_in[12];
    const float* W_ff2  = (const float*)d_in[13];
    const float* b_ff2  = (const float*)d_in[14];
    float* out = (float*)d_out;

    char* ws = (char*)d_ws;
    size_t off = 0;
    auto alloc = [&](size_t bytes) {
        char* p = ws + off;
        off += (bytes + 255) & ~(size_t)255;
        return p;
    };
    __bf16* wq_b   = (__bf16*)alloc((size_t)3072 * 1024 * 2);
    __bf16* wout_b = (__bf16*)alloc((size_t)1024 * 1024 * 2);
    __bf16* wg_b   = (__bf16*)alloc((size_t)1024 * 2048 * 2);
    __bf16* wf1_b  = (__bf16*)alloc((size_t)4096 * 1024 * 2);
    __bf16* wf2_b  = (__bf16*)alloc((size_t)1024 * 4096 * 2);
    __bf16* xn_b   = (__bf16*)alloc((size_t)2048 * 1024 * 2);
    __bf16* qkv_b  = (__bf16*)alloc((size_t)2048 * 3072 * 2);
    __bf16* cat_b  = (__bf16*)alloc((size_t)2048 * 2048 * 2);
    __bf16* a1_b   = (__bf16*)alloc((size_t)2048 * 1024 * 2);
    float*  h_f    = (float*)alloc((size_t)2048 * 1024 * 4);
    __bf16* hn_b   = (__bf16*)alloc((size_t)2048 * 1024 * 2);
    __bf16* e_b    = (__bf16*)alloc((size_t)2048 * 4096 * 2);
    float*  acc    = (float*)alloc(256);

    // weight casts
    cast_bf16_kernel<<<(3072 * 1024 / 8 + 255) / 256, 256, 0, stream>>>(W_qkv, wq_b, 3072 * 1024 / 8);
    cast_bf16_kernel<<<(1024 * 1024 / 8 + 255) / 256, 256, 0, stream>>>(W_out, wout_b, 1024 * 1024 / 8);
    cast_bf16_kernel<<<(1024 * 2048 / 8 + 255) / 256, 256, 0, stream>>>(W_gate, wg_b, 1024 * 2048 / 8);
    cast_bf16_kernel<<<(4096 * 1024 / 8 + 255) / 256, 256, 0, stream>>>(W_ff1, wf1_b, 4096 * 1024 / 8);
    cast_bf16_kernel<<<(1024 * 4096 / 8 + 255) / 256, 256, 0, stream>>>(W_ff2, wf2_b, 1024 * 4096 / 8);

    // LN1
    ln_kernel<<<2048, 256, 0, stream>>>(x, g1, b1, xn_b);
    // qkv = xn @ W_qkv^T
    gemm_nt<0><<<dim3(16, 24), 256, 0, stream>>>(xn_b, wq_b, nullptr, nullptr, qkv_b, nullptr, 2048, 3072, 1024);
    // attention -> cat
    attn_kernel<<<dim3(32, 16), 256, 0, stream>>>(qkv_b, lmask, cat_b);
    // a1 = cat @ W_gate^T + b_gate
    gemm_nt<0><<<dim3(16, 8), 256, 0, stream>>>(cat_b, wg_b, b_gate, nullptr, a1_b, nullptr, 2048, 1024, 2048);
    // h = x + a1 @ W_out^T
    gemm_nt<2><<<dim3(16, 8), 256, 0, stream>>>(a1_b, wout_b, nullptr, x, nullptr, h_f, 2048, 1024, 1024);
    // LN2
    ln_kernel<<<2048, 256, 0, stream>>>(h_f, g2, b2, hn_b);
    // e = gelu(hn @ W_ff1^T + b_ff1)
    gemm_nt<1><<<dim3(16, 32), 256, 0, stream>>>(hn_b, wf1_b, b_ff1, nullptr, e_b, nullptr, 2048, 4096, 1024);
    // out = h + e @ W_ff2^T + b_ff2
    gemm_nt<2><<<dim3(16, 8), 256, 0, stream>>>(e_b, wf2_b, b_ff2, h_f, nullptr, out, 2048, 1024, 4096);

    // sparsity scalar
    zero_acc_kernel<<<1, 1, 0, stream>>>(acc);
    sigmean_kernel<<<2048, 256, 0, stream>>>(lmask, acc);
    write_sp_kernel<<<1, 1, 0, stream>>>(acc, out);

    (void)in_sizes; (void)n_in; (void)out_size; (void)ws_size;
}

// Round 2
// 926.693 us; speedup vs baseline: 1.4441x; 1.4441x over previous
//
#include <hip/hip_runtime.h>
#include <hip/hip_bf16.h>

typedef __bf16 bf16x8 __attribute__((ext_vector_type(8)));
typedef float f32x4 __attribute__((ext_vector_type(4)));

#define MFMA16(a, b, c) __builtin_amdgcn_mfma_f32_16x16x32_bf16(a, b, c, 0, 0, 0)

#define T_SEQ 2048
#define D_MODEL 1024
#define N_HEADS 16
#define HEAD_DIM 64
#define D_FF 4096
#define QKV_STRIDE 3072

__device__ __forceinline__ float sigm(float x) { return 1.f / (1.f + __expf(-x)); }

// async global->LDS 16B copy; lds dst must be wave-uniform base + lane*16
__device__ __forceinline__ void g2l16(const __bf16* g, __bf16* l)
{
    __builtin_amdgcn_global_load_lds(
        (const __attribute__((address_space(1))) void*)g,
        (__attribute__((address_space(3))) void*)l, 16, 0, 0);
}

// ---------------- fp32 -> bf16 cast, 8 elements/thread ----------------
__global__ __launch_bounds__(256) void cast_bf16_kernel(
    const float* __restrict__ in, __bf16* __restrict__ out, int n8)
{
    int i = blockIdx.x * blockDim.x + threadIdx.x;
    if (i >= n8) return;
    const float4* p = (const float4*)in + (size_t)i * 2;
    float4 a = p[0], b = p[1];
    union { __bf16 h[8]; float4 v; } u;
    u.h[0] = (__bf16)a.x; u.h[1] = (__bf16)a.y; u.h[2] = (__bf16)a.z; u.h[3] = (__bf16)a.w;
    u.h[4] = (__bf16)b.x; u.h[5] = (__bf16)b.y; u.h[6] = (__bf16)b.z; u.h[7] = (__bf16)b.w;
    ((float4*)out)[i] = u.v;
}

// ---------------- LayerNorm: fp32 in -> bf16 out ----------------
__global__ __launch_bounds__(256) void ln_kernel(
    const float* __restrict__ x, const float* __restrict__ g,
    const float* __restrict__ b, __bf16* __restrict__ out)
{
    const int t = blockIdx.x;
    const int tid = threadIdx.x;
    float4 xv = *(const float4*)&x[t * D_MODEL + tid * 4];
    float s = xv.x + xv.y + xv.z + xv.w;
    float ss = xv.x * xv.x + xv.y * xv.y + xv.z * xv.z + xv.w * xv.w;
    for (int off = 1; off < 64; off <<= 1) {
        s += __shfl_xor(s, off);
        ss += __shfl_xor(ss, off);
    }
    __shared__ float sb[8];
    int w = tid >> 6, lane = tid & 63;
    if (lane == 0) { sb[w] = s; sb[4 + w] = ss; }
    __syncthreads();
    s = sb[0] + sb[1] + sb[2] + sb[3];
    ss = sb[4] + sb[5] + sb[6] + sb[7];
    float mu = s * (1.f / D_MODEL);
    float var = ss * (1.f / D_MODEL) - mu * mu;
    float rs = rsqrtf(var + 1e-5f);
    const float* xp = (const float*)&xv;
    for (int i = 0; i < 4; ++i) {
        int d = tid * 4 + i;
        out[t * D_MODEL + d] = (__bf16)((xp[i] - mu) * rs * g[d] + b[d]);
    }
}

// ---------------- NT GEMM (m97 pattern): C[m][n] = sum_k A[m][k]*B[n][k] ----
// BN fixed 128. BM=128: waves 2x2 of 64x64. BM=64: waves 1x4 of 64x32.
// EPI 0: bf16 out (+opt bias); EPI 1: bias + exact GELU -> bf16;
// EPI 2: fp32 out = resid + C (+opt bias).
// Epilogue round-trips C tile through LDS for full-line coalesced stores.
template<int BM, int EPI>
__global__ __launch_bounds__(256) void gemm_nt(
    const __bf16* __restrict__ A, const __bf16* __restrict__ B,
    const float* __restrict__ bias, const float* __restrict__ resid,
    __bf16* __restrict__ outb, float* __restrict__ outf,
    int M, int N, int K)
{
    constexpr int BN = 128;
    constexpr int EOUT = (EPI == 2) ? 4 : 2;
    constexpr int STAGE = (BM + BN) * 32 * 2;      // bytes for As+Bs
    constexpr int CTB = BM * BN * EOUT;            // bytes for C tile
    constexpr int SMEM = (STAGE > CTB) ? STAGE : CTB;
    __shared__ __align__(16) char smem[SMEM];
    __bf16* As = (__bf16*)smem;                    // [BM][32] unpadded
    __bf16* Bs = As + BM * 32;                     // [BN][32] unpadded

    const int tid = threadIdx.x;
    const int lane = tid & 63, w = tid >> 6;
    const int quad = lane >> 4, l16 = lane & 15;
    const int bm = blockIdx.x * BM, bn = blockIdx.y * BN;
    constexpr int NI = 4;                          // 64 rows per wave
    constexpr int NJ = (BM == 128) ? 4 : 2;
    const int wm = (BM == 128) ? (w & 1) * 64 : 0;
    const int wn = (BM == 128) ? (w >> 1) * 64 : w * 32;

    f32x4 acc[NI][NJ] = {};

    for (int k0 = 0; k0 < K; k0 += 32) {
        __syncthreads();
        constexpr int AIT = BM * 4 / 256;          // 16B chunks per thread for A
        for (int it = 0; it < AIT; ++it) {
            int c = it * 256 + tid;
            g2l16(&A[(size_t)(bm + (c >> 2)) * K + k0 + ((c & 3) << 3)], &As[c * 8]);
        }
        for (int it = 0; it < 2; ++it) {
            int c = it * 256 + tid;
            g2l16(&B[(size_t)(bn + (c >> 2)) * K + k0 + ((c & 3) << 3)], &Bs[c * 8]);
        }
        __syncthreads();
        bf16x8 af[NI], bfr[NJ];
        for (int i = 0; i < NI; ++i)
            af[i] = *(const bf16x8*)&As[(wm + i * 16 + l16) * 32 + quad * 8];
        for (int j = 0; j < NJ; ++j)
            bfr[j] = *(const bf16x8*)&Bs[(wn + j * 16 + l16) * 32 + quad * 8];
        for (int i = 0; i < NI; ++i)
            for (int j = 0; j < NJ; ++j)
                acc[i][j] = MFMA16(af[i], bfr[j], acc[i][j]);
    }

    __syncthreads();
    if (EPI == 2) {
        float* Ct = (float*)smem;
        for (int i = 0; i < NI; ++i)
            for (int j = 0; j < NJ; ++j)
                for (int r = 0; r < 4; ++r) {
                    int row = wm + i * 16 + quad * 4 + r;
                    int col = wn + j * 16 + l16;
                    float v = acc[i][j][r];
                    if (bias) v += bias[bn + col];
                    Ct[row * BN + col] = v;
                }
        __syncthreads();
        constexpr int IT = BM * BN / 4 / 256;
        for (int it = 0; it < IT; ++it) {
            int c = it * 256 + tid;
            int row = c >> 5, col = (c & 31) << 2;
            float4 v = *(float4*)&Ct[row * BN + col];
            size_t gi = (size_t)(bm + row) * N + bn + col;
            float4 r4 = *(const float4*)&resid[gi];
            v.x += r4.x; v.y += r4.y; v.z += r4.z; v.w += r4.w;
            *(float4*)&outf[gi] = v;
        }
    } else {
        __bf16* Ct = (__bf16*)smem;
        for (int i = 0; i < NI; ++i)
            for (int j = 0; j < NJ; ++j)
                for (int r = 0; r < 4; ++r) {
                    int row = wm + i * 16 + quad * 4 + r;
                    int col = wn + j * 16 + l16;
                    float v = acc[i][j][r];
                    if (bias) v += bias[bn + col];
                    if (EPI == 1) v = 0.5f * v * (1.f + erff(v * 0.70710678118f));
                    Ct[row * BN + col] = (__bf16)v;
                }
        __syncthreads();
        constexpr int IT = BM * BN / 8 / 256;
        for (int it = 0; it < IT; ++it) {
            int c = it * 256 + tid;
            int row = c >> 4, col = (c & 15) << 3;
            *(float4*)&outb[(size_t)(bm + row) * N + bn + col] = *(float4*)&Ct[row * BN + col];
        }
    }
}

// ---------------- fused dual-variant flash attention ----------------
__global__ __launch_bounds__(256) void attn_kernel(
    const __bf16* __restrict__ qkv, const float* __restrict__ lmask,
    __bf16* __restrict__ cat)
{
    __shared__ __bf16 Ks[32 * 80];     // [s][dh], stride 80
    __shared__ __bf16 Vt[64 * 48];     // [dh][s], stride 48
    __shared__ __bf16 Pw[4][16 * 48];  // per-wave P round-trip, stride 48

    const int tid = threadIdx.x;
    const int w = tid >> 6, lane = tid & 63;
    const int quad = lane >> 4, l16 = lane & 15;
    const int qt = blockIdx.x, h = blockIdx.y;
    const int q0 = qt * 64;

    const int tq = q0 + w * 16 + l16;
    bf16x8 qf[2];
    qf[0] = *(const bf16x8*)&qkv[(size_t)tq * QKV_STRIDE + h * 64 + quad * 8];
    qf[1] = *(const bf16x8*)&qkv[(size_t)tq * QKV_STRIDE + h * 64 + 32 + quad * 8];

    float m_[2][4], l_[2][4];
    f32x4 O[2][4] = {};
    for (int v = 0; v < 2; ++v)
        for (int r = 0; r < 4; ++r) { m_[v][r] = -1e30f; l_[v][r] = 0.f; }

    for (int s0 = 0; s0 < q0 + 64; s0 += 32) {
        __syncthreads();
        {
            int row = tid >> 3, c8 = (tid & 7) << 3;
            *(float4*)&Ks[row * 80 + c8] =
                *(const float4*)&qkv[(size_t)(s0 + row) * QKV_STRIDE + 1024 + h * 64 + c8];
            float4 vv = *(const float4*)&qkv[(size_t)(s0 + row) * QKV_STRIDE + 2048 + h * 64 + c8];
            const __bf16* vp = (const __bf16*)&vv;
            for (int j = 0; j < 8; ++j) Vt[(c8 + j) * 48 + row] = vp[j];
        }
        __syncthreads();

        f32x4 S[2];
        for (int c = 0; c < 2; ++c) {
            bf16x8 kf0 = *(const bf16x8*)&Ks[(c * 16 + l16) * 80 + quad * 8];
            bf16x8 kf1 = *(const bf16x8*)&Ks[(c * 16 + l16) * 80 + 32 + quad * 8];
            f32x4 z = {};
            z = MFMA16(qf[0], kf0, z);
            z = MFMA16(qf[1], kf1, z);
            S[c] = z * 0.125f;
        }

        float sig[2][4];
        bool msk[2][4];
        for (int c = 0; c < 2; ++c) {
            int sc = s0 + c * 16 + l16;
            for (int r = 0; r < 4; ++r) {
                int tr = q0 + w * 16 + quad * 4 + r;
                msk[c][r] = (sc > tr);
                sig[c][r] = sigm(lmask[((size_t)h * T_SEQ + tr) * T_SEQ + sc]);
            }
        }

        bf16x8 vf[4];
        for (int j = 0; j < 4; ++j)
            vf[j] = *(const bf16x8*)&Vt[(j * 16 + l16) * 48 + quad * 8];

        for (int v = 0; v < 2; ++v) {
            float p0[4], p1[4], mx[4];
            for (int r = 0; r < 4; ++r) {
                float a = msk[0][r] ? -1e30f : (v ? S[0][r] * sig[0][r] : S[0][r]);
                float b = msk[1][r] ? -1e30f : (v ? S[1][r] * sig[1][r] : S[1][r]);
                p0[r] = a; p1[r] = b;
                mx[r] = fmaxf(a, b);
            }
            for (int r = 0; r < 4; ++r)
                for (int off = 1; off < 16; off <<= 1)
                    mx[r] = fmaxf(mx[r], __shfl_xor(mx[r], off));
            float al[4];
            for (int r = 0; r < 4; ++r) {
                float mn = fmaxf(m_[v][r], mx[r]);
                al[r] = __expf(m_[v][r] - mn);
                m_[v][r] = mn;
                p0[r] = __expf(p0[r] - mn);
                p1[r] = __expf(p1[r] - mn);
                float rs = p0[r] + p1[r];
                for (int off = 1; off < 16; off <<= 1) rs += __shfl_xor(rs, off);
                l_[v][r] = l_[v][r] * al[r] + rs;
            }
            for (int j = 0; j < 4; ++j)
                for (int r = 0; r < 4; ++r) O[v][j][r] *= al[r];
            for (int r = 0; r < 4; ++r) {
                Pw[w][(quad * 4 + r) * 48 + l16] = (__bf16)p0[r];
                Pw[w][(quad * 4 + r) * 48 + 16 + l16] = (__bf16)p1[r];
            }
            bf16x8 pf = *(const bf16x8*)&Pw[w][l16 * 48 + quad * 8];
            for (int j = 0; j < 4; ++j)
                O[v][j] = MFMA16(pf, vf[j], O[v][j]);
        }
    }

    for (int v = 0; v < 2; ++v)
        for (int j = 0; j < 4; ++j)
            for (int r = 0; r < 4; ++r) {
                int tr = q0 + w * 16 + quad * 4 + r;
                int col = v * 1024 + h * 64 + j * 16 + l16;
                cat[(size_t)tr * 2048 + col] = (__bf16)(O[v][j][r] / l_[v][r]);
            }
}

// ---------------- sparsity scalar: mean(sigmoid(log_mask)) ----------------
__global__ void zero_acc_kernel(float* acc) { acc[0] = 0.f; }

__global__ __launch_bounds__(256) void sigmean_kernel(
    const float* __restrict__ lm, float* __restrict__ acc)
{
    const size_t total = (size_t)N_HEADS * T_SEQ * T_SEQ;
    size_t idx = ((size_t)blockIdx.x * 256 + threadIdx.x) * 4;
    const size_t stride = (size_t)gridDim.x * 256 * 4;
    float s = 0.f;
    for (size_t i = idx; i < total; i += stride) {
        float4 a = *(const float4*)&lm[i];
        s += sigm(a.x) + sigm(a.y) + sigm(a.z) + sigm(a.w);
    }
    for (int off = 1; off < 64; off <<= 1) s += __shfl_xor(s, off);
    __shared__ float sb[4];
    int w = threadIdx.x >> 6;
    if ((threadIdx.x & 63) == 0) sb[w] = s;
    __syncthreads();
    if (threadIdx.x == 0) atomicAdd(acc, sb[0] + sb[1] + sb[2] + sb[3]);
}

__global__ void write_sp_kernel(const float* __restrict__ acc, float* __restrict__ out)
{
    out[(size_t)T_SEQ * D_MODEL] = 0.0005f * acc[0] * (1.f / 67108864.f);
}

// ---------------- launch ----------------
extern "C" void kernel_launch(void* const* d_in, const int* in_sizes, int n_in,
                              void* d_out, int out_size, void* d_ws, size_t ws_size,
                              hipStream_t stream)
{
    const float* x      = (const float*)d_in[0];
    const float* W_qkv  = (const float*)d_in[2];
    const float* W_out  = (const float*)d_in[3];
    const float* lmask  = (const float*)d_in[4];
    const float* W_gate = (const float*)d_in[5];
    const float* b_gate = (const float*)d_in[6];
    const float* g1     = (const float*)d_in[7];
    const float* b1     = (const float*)d_in[8];
    const float* g2     = (const float*)d_in[9];
    const float* b2     = (const float*)d_in[10];
    const float* W_ff1  = (const float*)d_in[11];
    const float* b_ff1  = (const float*)d_in[12];
    const float* W_ff2  = (const float*)d_in[13];
    const float* b_ff2  = (const float*)d_in[14];
    float* out = (float*)d_out;

    char* ws = (char*)d_ws;
    size_t off = 0;
    auto alloc = [&](size_t bytes) {
        char* p = ws + off;
        off += (bytes + 255) & ~(size_t)255;
        return p;
    };
    __bf16* wq_b   = (__bf16*)alloc((size_t)3072 * 1024 * 2);
    __bf16* wout_b = (__bf16*)alloc((size_t)1024 * 1024 * 2);
    __bf16* wg_b   = (__bf16*)alloc((size_t)1024 * 2048 * 2);
    __bf16* wf1_b  = (__bf16*)alloc((size_t)4096 * 1024 * 2);
    __bf16* wf2_b  = (__bf16*)alloc((size_t)1024 * 4096 * 2);
    __bf16* xn_b   = (__bf16*)alloc((size_t)2048 * 1024 * 2);
    __bf16* qkv_b  = (__bf16*)alloc((size_t)2048 * 3072 * 2);
    __bf16* cat_b  = (__bf16*)alloc((size_t)2048 * 2048 * 2);
    __bf16* a1_b   = (__bf16*)alloc((size_t)2048 * 1024 * 2);
    float*  h_f    = (float*)alloc((size_t)2048 * 1024 * 4);
    __bf16* hn_b   = (__bf16*)alloc((size_t)2048 * 1024 * 2);
    __bf16* e_b    = (__bf16*)alloc((size_t)2048 * 4096 * 2);
    float*  acc    = (float*)alloc(256);

    cast_bf16_kernel<<<(3072 * 1024 / 8 + 255) / 256, 256, 0, stream>>>(W_qkv, wq_b, 3072 * 1024 / 8);
    cast_bf16_kernel<<<(1024 * 1024 / 8 + 255) / 256, 256, 0, stream>>>(W_out, wout_b, 1024 * 1024 / 8);
    cast_bf16_kernel<<<(1024 * 2048 / 8 + 255) / 256, 256, 0, stream>>>(W_gate, wg_b, 1024 * 2048 / 8);
    cast_bf16_kernel<<<(4096 * 1024 / 8 + 255) / 256, 256, 0, stream>>>(W_ff1, wf1_b, 4096 * 1024 / 8);
    cast_bf16_kernel<<<(1024 * 4096 / 8 + 255) / 256, 256, 0, stream>>>(W_ff2, wf2_b, 1024 * 4096 / 8);

    ln_kernel<<<2048, 256, 0, stream>>>(x, g1, b1, xn_b);
    gemm_nt<128, 0><<<dim3(16, 24), 256, 0, stream>>>(xn_b, wq_b, nullptr, nullptr, qkv_b, nullptr, 2048, 3072, 1024);
    attn_kernel<<<dim3(32, 16), 256, 0, stream>>>(qkv_b, lmask, cat_b);
    gemm_nt<64, 0><<<dim3(32, 8), 256, 0, stream>>>(cat_b, wg_b, b_gate, nullptr, a1_b, nullptr, 2048, 1024, 2048);
    gemm_nt<64, 2><<<dim3(32, 8), 256, 0, stream>>>(a1_b, wout_b, nullptr, x, nullptr, h_f, 2048, 1024, 1024);
    ln_kernel<<<2048, 256, 0, stream>>>(h_f, g2, b2, hn_b);
    gemm_nt<128, 1><<<dim3(16, 32), 256, 0, stream>>>(hn_b, wf1_b, b_ff1, nullptr, e_b, nullptr, 2048, 4096, 1024);
    gemm_nt<64, 2><<<dim3(32, 8), 256, 0, stream>>>(e_b, wf2_b, b_ff2, h_f, nullptr, out, 2048, 1024, 4096);

    zero_acc_kernel<<<1, 1, 0, stream>>>(acc);
    sigmean_kernel<<<2048, 256, 0, stream>>>(lmask, acc);
    write_sp_kernel<<<1, 1, 0, stream>>>(acc, out);

    (void)in_sizes; (void)n_in; (void)out_size; (void)ws_size;
}

// Round 3
// 866.049 us; speedup vs baseline: 1.5452x; 1.0700x over previous
//
#include <hip/hip_runtime.h>
#include <hip/hip_bf16.h>

typedef __bf16 bf16x8 __attribute__((ext_vector_type(8)));
typedef float f32x4 __attribute__((ext_vector_type(4)));

#define MFMA16(a, b, c) __builtin_amdgcn_mfma_f32_16x16x32_bf16(a, b, c, 0, 0, 0)

#define T_SEQ 2048
#define D_MODEL 1024
#define N_HEADS 16
#define HEAD_DIM 64
#define D_FF 4096
#define QKV_STRIDE 3072

__device__ __forceinline__ float sigm(float x) { return 1.f / (1.f + __expf(-x)); }

// async global->LDS 16B copy; lds dst must be wave-uniform base + lane*16
__device__ __forceinline__ void g2l16(const __bf16* g, __bf16* l)
{
    __builtin_amdgcn_global_load_lds(
        (const __attribute__((address_space(1))) void*)g,
        (__attribute__((address_space(3))) void*)l, 16, 0, 0);
}

// ---------------- fp32 -> bf16 cast, 8 elements/thread ----------------
__global__ __launch_bounds__(256) void cast_bf16_kernel(
    const float* __restrict__ in, __bf16* __restrict__ out, int n8)
{
    int i = blockIdx.x * blockDim.x + threadIdx.x;
    if (i >= n8) return;
    const float4* p = (const float4*)in + (size_t)i * 2;
    float4 a = p[0], b = p[1];
    union { __bf16 h[8]; float4 v; } u;
    u.h[0] = (__bf16)a.x; u.h[1] = (__bf16)a.y; u.h[2] = (__bf16)a.z; u.h[3] = (__bf16)a.w;
    u.h[4] = (__bf16)b.x; u.h[5] = (__bf16)b.y; u.h[6] = (__bf16)b.z; u.h[7] = (__bf16)b.w;
    ((float4*)out)[i] = u.v;
}

// ---------------- LayerNorm: fp32 in -> bf16 out ----------------
__global__ __launch_bounds__(256) void ln_kernel(
    const float* __restrict__ x, const float* __restrict__ g,
    const float* __restrict__ b, __bf16* __restrict__ out)
{
    const int t = blockIdx.x;
    const int tid = threadIdx.x;
    float4 xv = *(const float4*)&x[t * D_MODEL + tid * 4];
    float s = xv.x + xv.y + xv.z + xv.w;
    float ss = xv.x * xv.x + xv.y * xv.y + xv.z * xv.z + xv.w * xv.w;
    for (int off = 1; off < 64; off <<= 1) {
        s += __shfl_xor(s, off);
        ss += __shfl_xor(ss, off);
    }
    __shared__ float sb[8];
    int w = tid >> 6, lane = tid & 63;
    if (lane == 0) { sb[w] = s; sb[4 + w] = ss; }
    __syncthreads();
    s = sb[0] + sb[1] + sb[2] + sb[3];
    ss = sb[4] + sb[5] + sb[6] + sb[7];
    float mu = s * (1.f / D_MODEL);
    float var = ss * (1.f / D_MODEL) - mu * mu;
    float rs = rsqrtf(var + 1e-5f);
    const float* xp = (const float*)&xv;
    for (int i = 0; i < 4; ++i) {
        int d = tid * 4 + i;
        out[t * D_MODEL + d] = (__bf16)((xp[i] - mu) * rs * g[d] + b[d]);
    }
}

// ---------------- NT GEMM (m97 pattern) ----------------
template<int BM, int EPI>
__global__ __launch_bounds__(256) void gemm_nt(
    const __bf16* __restrict__ A, const __bf16* __restrict__ B,
    const float* __restrict__ bias, const float* __restrict__ resid,
    __bf16* __restrict__ outb, float* __restrict__ outf,
    int M, int N, int K)
{
    constexpr int BN = 128;
    constexpr int EOUT = (EPI == 2) ? 4 : 2;
    constexpr int STAGE = (BM + BN) * 32 * 2;
    constexpr int CTB = BM * BN * EOUT;
    constexpr int SMEM = (STAGE > CTB) ? STAGE : CTB;
    __shared__ __align__(16) char smem[SMEM];
    __bf16* As = (__bf16*)smem;
    __bf16* Bs = As + BM * 32;

    const int tid = threadIdx.x;
    const int lane = tid & 63, w = tid >> 6;
    const int quad = lane >> 4, l16 = lane & 15;
    const int bm = blockIdx.x * BM, bn = blockIdx.y * BN;
    constexpr int NI = 4;
    constexpr int NJ = (BM == 128) ? 4 : 2;
    const int wm = (BM == 128) ? (w & 1) * 64 : 0;
    const int wn = (BM == 128) ? (w >> 1) * 64 : w * 32;

    f32x4 acc[NI][NJ] = {};

    for (int k0 = 0; k0 < K; k0 += 32) {
        __syncthreads();
        constexpr int AIT = BM * 4 / 256;
        for (int it = 0; it < AIT; ++it) {
            int c = it * 256 + tid;
            g2l16(&A[(size_t)(bm + (c >> 2)) * K + k0 + ((c & 3) << 3)], &As[c * 8]);
        }
        for (int it = 0; it < 2; ++it) {
            int c = it * 256 + tid;
            g2l16(&B[(size_t)(bn + (c >> 2)) * K + k0 + ((c & 3) << 3)], &Bs[c * 8]);
        }
        __syncthreads();
        bf16x8 af[NI], bfr[NJ];
        for (int i = 0; i < NI; ++i)
            af[i] = *(const bf16x8*)&As[(wm + i * 16 + l16) * 32 + quad * 8];
        for (int j = 0; j < NJ; ++j)
            bfr[j] = *(const bf16x8*)&Bs[(wn + j * 16 + l16) * 32 + quad * 8];
        for (int i = 0; i < NI; ++i)
            for (int j = 0; j < NJ; ++j)
                acc[i][j] = MFMA16(af[i], bfr[j], acc[i][j]);
    }

    __syncthreads();
    if (EPI == 2) {
        float* Ct = (float*)smem;
        for (int i = 0; i < NI; ++i)
            for (int j = 0; j < NJ; ++j)
                for (int r = 0; r < 4; ++r) {
                    int row = wm + i * 16 + quad * 4 + r;
                    int col = wn + j * 16 + l16;
                    float v = acc[i][j][r];
                    if (bias) v += bias[bn + col];
                    Ct[row * BN + col] = v;
                }
        __syncthreads();
        constexpr int IT = BM * BN / 4 / 256;
        for (int it = 0; it < IT; ++it) {
            int c = it * 256 + tid;
            int row = c >> 5, col = (c & 31) << 2;
            float4 v = *(float4*)&Ct[row * BN + col];
            size_t gi = (size_t)(bm + row) * N + bn + col;
            float4 r4 = *(const float4*)&resid[gi];
            v.x += r4.x; v.y += r4.y; v.z += r4.z; v.w += r4.w;
            *(float4*)&outf[gi] = v;
        }
    } else {
        __bf16* Ct = (__bf16*)smem;
        for (int i = 0; i < NI; ++i)
            for (int j = 0; j < NJ; ++j)
                for (int r = 0; r < 4; ++r) {
                    int row = wm + i * 16 + quad * 4 + r;
                    int col = wn + j * 16 + l16;
                    float v = acc[i][j][r];
                    if (bias) v += bias[bn + col];
                    if (EPI == 1) v = 0.5f * v * (1.f + erff(v * 0.70710678118f));
                    Ct[row * BN + col] = (__bf16)v;
                }
        __syncthreads();
        constexpr int IT = BM * BN / 8 / 256;
        for (int it = 0; it < IT; ++it) {
            int c = it * 256 + tid;
            int row = c >> 4, col = (c & 15) << 3;
            *(float4*)&outb[(size_t)(bm + row) * N + bn + col] = *(float4*)&Ct[row * BN + col];
        }
    }
}

// ---------------- split-s dual-variant flash attention ----------------
// grid (80, 16): x = work item -> (qt, sp); 64 q-rows per block, s-range <= 512.
// Writes unnormalized partials (O' bf16, m/l fp32) + fused sigmoid-sum of the
// lmask rectangle it reads. Partial slot = h*80 + blockIdx.x.
__global__ __launch_bounds__(256) void attn_split_kernel(
    const __bf16* __restrict__ qkv, const float* __restrict__ lmask,
    __bf16* __restrict__ part_O, float2* __restrict__ part_ml,
    float* __restrict__ sigacc)
{
    __shared__ __bf16 Ks[64 * 72];     // [s][dh]
    __shared__ __bf16 Vt[64 * 72];     // [dh][s]
    __shared__ __bf16 Pw[4][16 * 72];  // per-wave P round-trip

    const int tid = threadIdx.x;
    const int w = tid >> 6, lane = tid & 63;
    const int quad = lane >> 4, l16 = lane & 15;
    const int idx = blockIdx.x, h = blockIdx.y;
    int qt, sp;
    if (idx < 8)       { qt = idx;                sp = 0; }
    else if (idx < 24) { qt = 8 + ((idx - 8) >> 1);  sp = (idx - 8) & 1; }
    else if (idx < 48) { qt = 16 + (idx - 24) / 3;   sp = (idx - 24) % 3; }
    else               { qt = 24 + ((idx - 48) >> 2); sp = (idx - 48) & 3; }
    const int q0 = qt * 64;
    const int sbeg = sp * 512;
    const int send = min(sbeg + 512, q0 + 64);

    const int tq = q0 + w * 16 + l16;
    bf16x8 qf0 = *(const bf16x8*)&qkv[(size_t)tq * QKV_STRIDE + h * 64 + quad * 8];
    bf16x8 qf1 = *(const bf16x8*)&qkv[(size_t)tq * QKV_STRIDE + h * 64 + 32 + quad * 8];

    float m_[2][4], l_[2][4];
    f32x4 O[2][4] = {};
    for (int v = 0; v < 2; ++v)
        for (int r = 0; r < 4; ++r) { m_[v][r] = -1e30f; l_[v][r] = 0.f; }
    float sigsum = 0.f;
    const int trow = q0 + w * 16 + quad * 4;  // + r

    for (int s0 = sbeg; s0 < send; s0 += 64) {
        // hoisted lmask loads (latency overlaps staging)
        float lm[4][4];
        for (int c = 0; c < 4; ++c) {
            const float* lp = &lmask[((size_t)h * T_SEQ + trow) * T_SEQ + s0 + c * 16 + l16];
            for (int r = 0; r < 4; ++r) lm[c][r] = lp[(size_t)r * T_SEQ];
        }
        __syncthreads();
        for (int it = 0; it < 2; ++it) {
            int c = it * 256 + tid;
            int row = c >> 3, c8 = (c & 7) << 3;
            *(float4*)&Ks[row * 72 + c8] =
                *(const float4*)&qkv[(size_t)(s0 + row) * QKV_STRIDE + 1024 + h * 64 + c8];
            float4 vv = *(const float4*)&qkv[(size_t)(s0 + row) * QKV_STRIDE + 2048 + h * 64 + c8];
            const __bf16* vp = (const __bf16*)&vv;
            for (int j = 0; j < 8; ++j) Vt[(c8 + j) * 72 + row] = vp[j];
        }
        __syncthreads();

        f32x4 S[4];
        for (int c = 0; c < 4; ++c) {
            bf16x8 kf0 = *(const bf16x8*)&Ks[(c * 16 + l16) * 72 + quad * 8];
            bf16x8 kf1 = *(const bf16x8*)&Ks[(c * 16 + l16) * 72 + 32 + quad * 8];
            f32x4 z = {};
            z = MFMA16(qf0, kf0, z);
            z = MFMA16(qf1, kf1, z);
            S[c] = z * 0.125f;
        }
        bf16x8 vf[4][2];
        for (int j = 0; j < 4; ++j) {
            vf[j][0] = *(const bf16x8*)&Vt[(j * 16 + l16) * 72 + quad * 8];
            vf[j][1] = *(const bf16x8*)&Vt[(j * 16 + l16) * 72 + 32 + quad * 8];
        }

        for (int v = 0; v < 2; ++v) {
            float p[4][4];
            for (int c = 0; c < 4; ++c) {
                int sc = s0 + c * 16 + l16;
                for (int r = 0; r < 4; ++r) {
                    float val;
                    if (v == 0) val = S[c][r];
                    else {
                        float sg = sigm(lm[c][r]);
                        sigsum += sg;
                        val = S[c][r] * sg;
                    }
                    p[c][r] = (sc > trow + r) ? -1e30f : val;
                }
            }
            float al[4];
            for (int r = 0; r < 4; ++r) {
                float mx = fmaxf(fmaxf(p[0][r], p[1][r]), fmaxf(p[2][r], p[3][r]));
                for (int off = 1; off < 16; off <<= 1)
                    mx = fmaxf(mx, __shfl_xor(mx, off));
                float mn = fmaxf(m_[v][r], mx);
                al[r] = __expf(m_[v][r] - mn);
                m_[v][r] = mn;
                float s = 0.f;
                for (int c = 0; c < 4; ++c) {
                    p[c][r] = __expf(p[c][r] - mn);
                    s += p[c][r];
                }
                for (int off = 1; off < 16; off <<= 1) s += __shfl_xor(s, off);
                l_[v][r] = l_[v][r] * al[r] + s;
            }
            for (int j = 0; j < 4; ++j)
                for (int r = 0; r < 4; ++r) O[v][j][r] *= al[r];
            for (int c = 0; c < 4; ++c)
                for (int r = 0; r < 4; ++r)
                    Pw[w][(quad * 4 + r) * 72 + c * 16 + l16] = (__bf16)p[c][r];
            bf16x8 pf0 = *(const bf16x8*)&Pw[w][l16 * 72 + quad * 8];
            bf16x8 pf1 = *(const bf16x8*)&Pw[w][l16 * 72 + 32 + quad * 8];
            for (int j = 0; j < 4; ++j) {
                O[v][j] = MFMA16(pf0, vf[j][0], O[v][j]);
                O[v][j] = MFMA16(pf1, vf[j][1], O[v][j]);
            }
        }
    }

    const size_t slot = (size_t)h * 80 + idx;
    for (int v = 0; v < 2; ++v)
        for (int j = 0; j < 4; ++j)
            for (int r = 0; r < 4; ++r) {
                int row = w * 16 + quad * 4 + r;
                part_O[((slot * 2 + v) * 64 + row) * 64 + j * 16 + l16] = (__bf16)O[v][j][r];
            }
    if (l16 == 0)
        for (int v = 0; v < 2; ++v)
            for (int r = 0; r < 4; ++r) {
                int row = w * 16 + quad * 4 + r;
                part_ml[(slot * 2 + v) * 64 + row] = make_float2(m_[v][r], l_[v][r]);
            }
    for (int off = 1; off < 64; off <<= 1) sigsum += __shfl_xor(sigsum, off);
    if (lane == 0) atomicAdd(sigacc, sigsum);
}

// ---------------- combine partials -> cat ----------------
__global__ __launch_bounds__(256) void attn_combine_kernel(
    const __bf16* __restrict__ part_O, const float2* __restrict__ part_ml,
    __bf16* __restrict__ cat)
{
    const int qt = blockIdx.x, h = blockIdx.y;
    const int nsp = (qt >> 3) + 1;
    const int base = (qt < 8) ? qt : (qt < 16) ? 8 + (qt - 8) * 2
                   : (qt < 24) ? 24 + (qt - 16) * 3 : 48 + (qt - 24) * 4;
    const int tid = threadIdx.x;
    const int row = tid >> 2, v = (tid >> 1) & 1, colh = (tid & 1) * 32;

    float2 ml[4];
    float M = -1e30f;
    for (int p = 0; p < nsp; ++p) {
        ml[p] = part_ml[(((size_t)h * 80 + base + p) * 2 + v) * 64 + row];
        M = fmaxf(M, ml[p].x);
    }
    float L = 0.f;
    float acc[32] = {};
    for (int p = 0; p < nsp; ++p) {
        float sc = __expf(ml[p].x - M);
        L += sc * ml[p].y;
        const __bf16* src =
            &part_O[((((size_t)h * 80 + base + p) * 2 + v) * 64 + row) * 64 + colh];
        for (int k = 0; k < 4; ++k) {
            bf16x8 o = *(const bf16x8*)&src[k * 8];
            for (int e = 0; e < 8; ++e) acc[k * 8 + e] += sc * (float)o[e];
        }
    }
    float inv = 1.f / L;
    __bf16* dst = &cat[(size_t)(qt * 64 + row) * 2048 + v * 1024 + h * 64 + colh];
    for (int k = 0; k < 4; ++k) {
        union { __bf16 hh[8]; float4 f4; } u;
        for (int e = 0; e < 8; ++e) u.hh[e] = (__bf16)(acc[k * 8 + e] * inv);
        *(float4*)&dst[k * 8] = u.f4;
    }
}

// ---------------- sigmoid-sum over strict upper tiles ----------------
__global__ void zero_acc_kernel(float* acc) { acc[0] = 0.f; }

__global__ __launch_bounds__(256) void sigmean_upper_kernel(
    const float* __restrict__ lm, float* __restrict__ acc)
{
    const int qt = blockIdx.x, h = blockIdx.y, rg = blockIdx.z;
    const int sc0 = (qt + 1) * 64;
    const int len4 = (T_SEQ - sc0) >> 2;
    float s = 0.f;
    for (int r = 0; r < 16; ++r) {
        const float* rowp = &lm[((size_t)h * T_SEQ + qt * 64 + rg * 16 + r) * T_SEQ + sc0];
        for (int c = threadIdx.x; c < len4; c += 256) {
            float4 a = *(const float4*)&rowp[c * 4];
            s += sigm(a.x) + sigm(a.y) + sigm(a.z) + sigm(a.w);
        }
    }
    for (int off = 1; off < 64; off <<= 1) s += __shfl_xor(s, off);
    if ((threadIdx.x & 63) == 0) atomicAdd(acc, s);
}

__global__ void write_sp_kernel(const float* __restrict__ acc, float* __restrict__ out)
{
    out[(size_t)T_SEQ * D_MODEL] = 0.0005f * acc[0] * (1.f / 67108864.f);
}

// ---------------- launch ----------------
extern "C" void kernel_launch(void* const* d_in, const int* in_sizes, int n_in,
                              void* d_out, int out_size, void* d_ws, size_t ws_size,
                              hipStream_t stream)
{
    const float* x      = (const float*)d_in[0];
    const float* W_qkv  = (const float*)d_in[2];
    const float* W_out  = (const float*)d_in[3];
    const float* lmask  = (const float*)d_in[4];
    const float* W_gate = (const float*)d_in[5];
    const float* b_gate = (const float*)d_in[6];
    const float* g1     = (const float*)d_in[7];
    const float* b1     = (const float*)d_in[8];
    const float* g2     = (const float*)d_in[9];
    const float* b2     = (const float*)d_in[10];
    const float* W_ff1  = (const float*)d_in[11];
    const float* b_ff1  = (const float*)d_in[12];
    const float* W_ff2  = (const float*)d_in[13];
    const float* b_ff2  = (const float*)d_in[14];
    float* out = (float*)d_out;

    char* ws = (char*)d_ws;
    size_t off = 0;
    auto alloc = [&](size_t bytes) {
        char* p = ws + off;
        off += (bytes + 255) & ~(size_t)255;
        return p;
    };
    __bf16* wq_b   = (__bf16*)alloc((size_t)3072 * 1024 * 2);
    __bf16* wout_b = (__bf16*)alloc((size_t)1024 * 1024 * 2);
    __bf16* wg_b   = (__bf16*)alloc((size_t)1024 * 2048 * 2);
    __bf16* wf1_b  = (__bf16*)alloc((size_t)4096 * 1024 * 2);
    __bf16* wf2_b  = (__bf16*)alloc((size_t)1024 * 4096 * 2);
    __bf16* xn_b   = (__bf16*)alloc((size_t)2048 * 1024 * 2);
    __bf16* qkv_b  = (__bf16*)alloc((size_t)2048 * 3072 * 2);
    __bf16* cat_b  = (__bf16*)alloc((size_t)2048 * 2048 * 2);
    __bf16* a1_b   = (__bf16*)alloc((size_t)2048 * 1024 * 2);
    float*  h_f    = (float*)alloc((size_t)2048 * 1024 * 4);
    __bf16* hn_b   = (__bf16*)alloc((size_t)2048 * 1024 * 2);
    __bf16* e_b    = (__bf16*)alloc((size_t)2048 * 4096 * 2);
    __bf16* part_O = (__bf16*)alloc((size_t)16 * 80 * 2 * 64 * 64 * 2);
    float2* part_ml= (float2*)alloc((size_t)16 * 80 * 2 * 64 * 8);
    float*  acc    = (float*)alloc(256);

    zero_acc_kernel<<<1, 1, 0, stream>>>(acc);

    cast_bf16_kernel<<<(3072 * 1024 / 8 + 255) / 256, 256, 0, stream>>>(W_qkv, wq_b, 3072 * 1024 / 8);
    cast_bf16_kernel<<<(1024 * 1024 / 8 + 255) / 256, 256, 0, stream>>>(W_out, wout_b, 1024 * 1024 / 8);
    cast_bf16_kernel<<<(1024 * 2048 / 8 + 255) / 256, 256, 0, stream>>>(W_gate, wg_b, 1024 * 2048 / 8);
    cast_bf16_kernel<<<(4096 * 1024 / 8 + 255) / 256, 256, 0, stream>>>(W_ff1, wf1_b, 4096 * 1024 / 8);
    cast_bf16_kernel<<<(1024 * 4096 / 8 + 255) / 256, 256, 0, stream>>>(W_ff2, wf2_b, 1024 * 4096 / 8);

    ln_kernel<<<2048, 256, 0, stream>>>(x, g1, b1, xn_b);
    gemm_nt<128, 0><<<dim3(16, 24), 256, 0, stream>>>(xn_b, wq_b, nullptr, nullptr, qkv_b, nullptr, 2048, 3072, 1024);
    attn_split_kernel<<<dim3(80, 16), 256, 0, stream>>>(qkv_b, lmask, part_O, part_ml, acc);
    attn_combine_kernel<<<dim3(32, 16), 256, 0, stream>>>(part_O, part_ml, cat_b);
    sigmean_upper_kernel<<<dim3(32, 16, 4), 256, 0, stream>>>(lmask, acc);

    gemm_nt<64, 0><<<dim3(32, 8), 256, 0, stream>>>(cat_b, wg_b, b_gate, nullptr, a1_b, nullptr, 2048, 1024, 2048);
    gemm_nt<64, 2><<<dim3(32, 8), 256, 0, stream>>>(a1_b, wout_b, nullptr, x, nullptr, h_f, 2048, 1024, 1024);
    ln_kernel<<<2048, 256, 0, stream>>>(h_f, g2, b2, hn_b);
    gemm_nt<128, 1><<<dim3(16, 32), 256, 0, stream>>>(hn_b, wf1_b, b_ff1, nullptr, e_b, nullptr, 2048, 4096, 1024);
    gemm_nt<64, 2><<<dim3(32, 8), 256, 0, stream>>>(e_b, wf2_b, b_ff2, h_f, nullptr, out, 2048, 1024, 4096);

    write_sp_kernel<<<1, 1, 0, stream>>>(acc, out);

    (void)in_sizes; (void)n_in; (void)out_size; (void)ws_size;
}

// Round 4
// 814.200 us; speedup vs baseline: 1.6436x; 1.0637x over previous
//
#include <hip/hip_runtime.h>
#include <hip/hip_bf16.h>

typedef __bf16 bf16x8 __attribute__((ext_vector_type(8)));
typedef float f32x4 __attribute__((ext_vector_type(4)));

#define MFMA16(a, b, c) __builtin_amdgcn_mfma_f32_16x16x32_bf16(a, b, c, 0, 0, 0)

#define T_SEQ 2048
#define D_MODEL 1024
#define N_HEADS 16
#define HEAD_DIM 64
#define D_FF 4096
#define QKV_STRIDE 3072

__device__ __forceinline__ float sigm(float x) { return 1.f / (1.f + __expf(-x)); }

// async global->LDS 16B copy; lds dst must be wave-uniform base + lane*16
__device__ __forceinline__ void g2l16(const __bf16* g, __bf16* l)
{
    __builtin_amdgcn_global_load_lds(
        (const __attribute__((address_space(1))) void*)g,
        (__attribute__((address_space(3))) void*)l, 16, 0, 0);
}

// 16-lane rotational max-reduce on the VALU pipe (DPP row_ror), no LDS traffic
template<int CTRL>
__device__ __forceinline__ float dpp_max_step(float x)
{
    int xi = __builtin_bit_cast(int, x);
    int yi = __builtin_amdgcn_update_dpp(xi, xi, CTRL, 0xf, 0xf, true);
    return fmaxf(x, __builtin_bit_cast(float, yi));
}
__device__ __forceinline__ float rmax16(float x)
{
    x = dpp_max_step<0x121>(x);  // row_ror:1
    x = dpp_max_step<0x122>(x);  // row_ror:2
    x = dpp_max_step<0x124>(x);  // row_ror:4
    x = dpp_max_step<0x128>(x);  // row_ror:8
    return x;
}

// ---------------- fp32 -> bf16 cast, 8 elements/thread ----------------
__global__ __launch_bounds__(256) void cast_bf16_kernel(
    const float* __restrict__ in, __bf16* __restrict__ out, int n8)
{
    int i = blockIdx.x * blockDim.x + threadIdx.x;
    if (i >= n8) return;
    const float4* p = (const float4*)in + (size_t)i * 2;
    float4 a = p[0], b = p[1];
    union { __bf16 h[8]; float4 v; } u;
    u.h[0] = (__bf16)a.x; u.h[1] = (__bf16)a.y; u.h[2] = (__bf16)a.z; u.h[3] = (__bf16)a.w;
    u.h[4] = (__bf16)b.x; u.h[5] = (__bf16)b.y; u.h[6] = (__bf16)b.z; u.h[7] = (__bf16)b.w;
    ((float4*)out)[i] = u.v;
}

// ---------------- LayerNorm: fp32 in -> bf16 out ----------------
__global__ __launch_bounds__(256) void ln_kernel(
    const float* __restrict__ x, const float* __restrict__ g,
    const float* __restrict__ b, __bf16* __restrict__ out)
{
    const int t = blockIdx.x;
    const int tid = threadIdx.x;
    float4 xv = *(const float4*)&x[t * D_MODEL + tid * 4];
    float s = xv.x + xv.y + xv.z + xv.w;
    float ss = xv.x * xv.x + xv.y * xv.y + xv.z * xv.z + xv.w * xv.w;
    for (int off = 1; off < 64; off <<= 1) {
        s += __shfl_xor(s, off);
        ss += __shfl_xor(ss, off);
    }
    __shared__ float sb[8];
    int w = tid >> 6, lane = tid & 63;
    if (lane == 0) { sb[w] = s; sb[4 + w] = ss; }
    __syncthreads();
    s = sb[0] + sb[1] + sb[2] + sb[3];
    ss = sb[4] + sb[5] + sb[6] + sb[7];
    float mu = s * (1.f / D_MODEL);
    float var = ss * (1.f / D_MODEL) - mu * mu;
    float rs = rsqrtf(var + 1e-5f);
    const float* xp = (const float*)&xv;
    for (int i = 0; i < 4; ++i) {
        int d = tid * 4 + i;
        out[t * D_MODEL + d] = (__bf16)((xp[i] - mu) * rs * g[d] + b[d]);
    }
}

// ---------------- NT GEMM, BK=64 (two m97-layout half-tiles/iter) ----------
template<int BM, int EPI>
__global__ __launch_bounds__(256) void gemm_nt(
    const __bf16* __restrict__ A, const __bf16* __restrict__ B,
    const float* __restrict__ bias, const float* __restrict__ resid,
    __bf16* __restrict__ outb, float* __restrict__ outf,
    int M, int N, int K)
{
    constexpr int BN = 128;
    constexpr int EOUT = (EPI == 2) ? 4 : 2;
    constexpr int STAGE = (BM + BN) * 64 * 2;
    constexpr int CTB = BM * BN * EOUT;
    constexpr int SMEM = (STAGE > CTB) ? STAGE : CTB;
    __shared__ __align__(16) char smem[SMEM];
    __bf16* As = (__bf16*)smem;        // As0[BM][32], As1[BM][32]
    __bf16* Bs = As + BM * 64;         // Bs0[BN][32], Bs1[BN][32]

    const int tid = threadIdx.x;
    const int lane = tid & 63, w = tid >> 6;
    const int quad = lane >> 4, l16 = lane & 15;
    const int bm = blockIdx.x * BM, bn = blockIdx.y * BN;
    constexpr int NI = 4;
    constexpr int NJ = (BM == 128) ? 4 : 2;
    const int wm = (BM == 128) ? (w & 1) * 64 : 0;
    const int wn = (BM == 128) ? (w >> 1) * 64 : w * 32;

    f32x4 acc[NI][NJ] = {};

    for (int k0 = 0; k0 < K; k0 += 64) {
        __syncthreads();
        constexpr int AIT = BM * 8 / 256;          // 16B chunks/thread for A
        for (int it = 0; it < AIT; ++it) {
            int c = it * 256 + tid;
            int tile = (c >= BM * 4) ? 1 : 0;
            int c2 = c & (BM * 4 - 1);
            g2l16(&A[(size_t)(bm + (c2 >> 2)) * K + k0 + tile * 32 + ((c2 & 3) << 3)],
                  &As[c * 8]);
        }
        for (int it = 0; it < 4; ++it) {
            int c = it * 256 + tid;
            int tile = (c >= 512) ? 1 : 0;
            int c2 = c & 511;
            g2l16(&B[(size_t)(bn + (c2 >> 2)) * K + k0 + tile * 32 + ((c2 & 3) << 3)],
                  &Bs[c * 8]);
        }
        __syncthreads();
        for (int ks = 0; ks < 2; ++ks) {
            bf16x8 af[NI], bfr[NJ];
            for (int i = 0; i < NI; ++i)
                af[i] = *(const bf16x8*)&As[ks * BM * 32 + (wm + i * 16 + l16) * 32 + quad * 8];
            for (int j = 0; j < NJ; ++j)
                bfr[j] = *(const bf16x8*)&Bs[ks * BN * 32 + (wn + j * 16 + l16) * 32 + quad * 8];
            for (int i = 0; i < NI; ++i)
                for (int j = 0; j < NJ; ++j)
                    acc[i][j] = MFMA16(af[i], bfr[j], acc[i][j]);
        }
    }

    __syncthreads();
    if (EPI == 2) {
        float* Ct = (float*)smem;
        for (int i = 0; i < NI; ++i)
            for (int j = 0; j < NJ; ++j)
                for (int r = 0; r < 4; ++r) {
                    int row = wm + i * 16 + quad * 4 + r;
                    int col = wn + j * 16 + l16;
                    float v = acc[i][j][r];
                    if (bias) v += bias[bn + col];
                    Ct[row * BN + col] = v;
                }
        __syncthreads();
        constexpr int IT = BM * BN / 4 / 256;
        for (int it = 0; it < IT; ++it) {
            int c = it * 256 + tid;
            int row = c >> 5, col = (c & 31) << 2;
            float4 v = *(float4*)&Ct[row * BN + col];
            size_t gi = (size_t)(bm + row) * N + bn + col;
            float4 r4 = *(const float4*)&resid[gi];
            v.x += r4.x; v.y += r4.y; v.z += r4.z; v.w += r4.w;
            *(float4*)&outf[gi] = v;
        }
    } else {
        __bf16* Ct = (__bf16*)smem;
        for (int i = 0; i < NI; ++i)
            for (int j = 0; j < NJ; ++j)
                for (int r = 0; r < 4; ++r) {
                    int row = wm + i * 16 + quad * 4 + r;
                    int col = wn + j * 16 + l16;
                    float v = acc[i][j][r];
                    if (bias) v += bias[bn + col];
                    if (EPI == 1) v = 0.5f * v * (1.f + erff(v * 0.70710678118f));
                    Ct[row * BN + col] = (__bf16)v;
                }
        __syncthreads();
        constexpr int IT = BM * BN / 8 / 256;
        for (int it = 0; it < IT; ++it) {
            int c = it * 256 + tid;
            int row = c >> 4, col = (c & 15) << 3;
            *(float4*)&outb[(size_t)(bm + row) * N + bn + col] = *(float4*)&Ct[row * BN + col];
        }
    }
}

// ---------------- split-s dual-variant flash attention ----------------
__global__ __launch_bounds__(256) void attn_split_kernel(
    const __bf16* __restrict__ qkv, const float* __restrict__ lmask,
    __bf16* __restrict__ part_O, float2* __restrict__ part_ml,
    float* __restrict__ sigacc)
{
    __shared__ __bf16 Ks[64 * 64];     // Ks0[s][32], Ks1[s][32]
    __shared__ __bf16 Vt[64 * 72];     // [dh][s]
    __shared__ __bf16 Pw[4][16 * 72];  // per-wave P round-trip

    const int tid = threadIdx.x;
    const int w = tid >> 6, lane = tid & 63;
    const int quad = lane >> 4, l16 = lane & 15;
    const int idx = blockIdx.x, h = blockIdx.y;
    int qt, sp;
    if (idx < 8)       { qt = idx;                sp = 0; }
    else if (idx < 24) { qt = 8 + ((idx - 8) >> 1);  sp = (idx - 8) & 1; }
    else if (idx < 48) { qt = 16 + (idx - 24) / 3;   sp = (idx - 24) % 3; }
    else               { qt = 24 + ((idx - 48) >> 2); sp = (idx - 48) & 3; }
    const int q0 = qt * 64;
    const int sbeg = sp * 512;
    const int send = min(sbeg + 512, q0 + 64);

    const int tq = q0 + w * 16 + l16;
    bf16x8 qf0 = *(const bf16x8*)&qkv[(size_t)tq * QKV_STRIDE + h * 64 + quad * 8];
    bf16x8 qf1 = *(const bf16x8*)&qkv[(size_t)tq * QKV_STRIDE + h * 64 + 32 + quad * 8];

    bf16x8 ones;
    for (int e = 0; e < 8; ++e) ones[e] = (__bf16)1.0f;

    float m_[2][4], l_[2][4];
    f32x4 O[2][4] = {};
    for (int v = 0; v < 2; ++v)
        for (int r = 0; r < 4; ++r) { m_[v][r] = -1e30f; l_[v][r] = 0.f; }
    float sigsum = 0.f;
    const int trow = q0 + w * 16 + quad * 4;  // + r

    for (int s0 = sbeg; s0 < send; s0 += 64) {
        // hoisted lmask loads (latency overlaps staging)
        float lm[4][4];
        for (int c = 0; c < 4; ++c) {
            const float* lp = &lmask[((size_t)h * T_SEQ + trow) * T_SEQ + s0 + c * 16 + l16];
            for (int r = 0; r < 4; ++r) lm[c][r] = lp[(size_t)r * T_SEQ];
        }
        __syncthreads();
        // K: async g2l16 into two [64][32] half-tiles
        for (int it = 0; it < 2; ++it) {
            int c = it * 256 + tid;
            int tile = c >> 8;
            int c2 = c & 255;
            g2l16(&qkv[(size_t)(s0 + (c2 >> 2)) * QKV_STRIDE + 1024 + h * 64 + tile * 32 + ((c2 & 3) << 3)],
                  &Ks[c * 8]);
        }
        // V: transpose scatter via VGPR
        for (int it = 0; it < 2; ++it) {
            int c = it * 256 + tid;
            int row = c >> 3, c8 = (c & 7) << 3;
            float4 vv = *(const float4*)&qkv[(size_t)(s0 + row) * QKV_STRIDE + 2048 + h * 64 + c8];
            const __bf16* vp = (const __bf16*)&vv;
            for (int j = 0; j < 8; ++j) Vt[(c8 + j) * 72 + row] = vp[j];
        }
        __syncthreads();

        f32x4 S[4];
        for (int c = 0; c < 4; ++c) {
            bf16x8 kf0 = *(const bf16x8*)&Ks[(c * 16 + l16) * 32 + quad * 8];
            bf16x8 kf1 = *(const bf16x8*)&Ks[2048 + (c * 16 + l16) * 32 + quad * 8];
            f32x4 z = {};
            z = MFMA16(qf0, kf0, z);
            z = MFMA16(qf1, kf1, z);
            S[c] = z * 0.125f;
        }
        bf16x8 vf[4][2];
        for (int j = 0; j < 4; ++j) {
            vf[j][0] = *(const bf16x8*)&Vt[(j * 16 + l16) * 72 + quad * 8];
            vf[j][1] = *(const bf16x8*)&Vt[(j * 16 + l16) * 72 + 32 + quad * 8];
        }

        float sig[4][4];
        for (int c = 0; c < 4; ++c)
            for (int r = 0; r < 4; ++r) {
                sig[c][r] = sigm(lm[c][r]);
                sigsum += sig[c][r];
            }

        for (int v = 0; v < 2; ++v) {
            float p[4][4];
            for (int c = 0; c < 4; ++c) {
                int sc = s0 + c * 16 + l16;
                for (int r = 0; r < 4; ++r) {
                    float val = v ? S[c][r] * sig[c][r] : S[c][r];
                    p[c][r] = (sc > trow + r) ? -1e30f : val;
                }
            }
            float al[4];
            for (int r = 0; r < 4; ++r) {
                float mx = fmaxf(fmaxf(p[0][r], p[1][r]), fmaxf(p[2][r], p[3][r]));
                mx = rmax16(mx);                       // DPP, VALU-only
                float mn = fmaxf(m_[v][r], mx);
                al[r] = __expf(m_[v][r] - mn);
                m_[v][r] = mn;
                for (int c = 0; c < 4; ++c)
                    p[c][r] = __expf(p[c][r] - mn);
            }
            for (int j = 0; j < 4; ++j)
                for (int r = 0; r < 4; ++r) O[v][j][r] *= al[r];
            for (int c = 0; c < 4; ++c)
                for (int r = 0; r < 4; ++r)
                    Pw[w][(quad * 4 + r) * 72 + c * 16 + l16] = (__bf16)p[c][r];
            bf16x8 pf0 = *(const bf16x8*)&Pw[w][l16 * 72 + quad * 8];
            bf16x8 pf1 = *(const bf16x8*)&Pw[w][l16 * 72 + 32 + quad * 8];
            f32x4 rs = {};
            rs = MFMA16(pf0, ones, rs);               // row-sum via matrix pipe
            rs = MFMA16(pf1, ones, rs);
            for (int j = 0; j < 4; ++j) {
                O[v][j] = MFMA16(pf0, vf[j][0], O[v][j]);
                O[v][j] = MFMA16(pf1, vf[j][1], O[v][j]);
            }
            for (int r = 0; r < 4; ++r)
                l_[v][r] = l_[v][r] * al[r] + rs[r];
        }
    }

    const size_t slot = (size_t)h * 80 + idx;
    for (int v = 0; v < 2; ++v)
        for (int j = 0; j < 4; ++j)
            for (int r = 0; r < 4; ++r) {
                int row = w * 16 + quad * 4 + r;
                part_O[((slot * 2 + v) * 64 + row) * 64 + j * 16 + l16] = (__bf16)O[v][j][r];
            }
    if (l16 == 0)
        for (int v = 0; v < 2; ++v)
            for (int r = 0; r < 4; ++r) {
                int row = w * 16 + quad * 4 + r;
                part_ml[(slot * 2 + v) * 64 + row] = make_float2(m_[v][r], l_[v][r]);
            }
    for (int off = 1; off < 64; off <<= 1) sigsum += __shfl_xor(sigsum, off);
    if (lane == 0) atomicAdd(sigacc, sigsum);
}

// ---------------- combine partials -> cat ----------------
__global__ __launch_bounds__(256) void attn_combine_kernel(
    const __bf16* __restrict__ part_O, const float2* __restrict__ part_ml,
    __bf16* __restrict__ cat)
{
    const int qt = blockIdx.x, h = blockIdx.y;
    const int nsp = (qt >> 3) + 1;
    const int base = (qt < 8) ? qt : (qt < 16) ? 8 + (qt - 8) * 2
                   : (qt < 24) ? 24 + (qt - 16) * 3 : 48 + (qt - 24) * 4;
    const int tid = threadIdx.x;
    const int row = tid >> 2, v = (tid >> 1) & 1, colh = (tid & 1) * 32;

    float2 ml[4];
    float M = -1e30f;
    for (int p = 0; p < nsp; ++p) {
        ml[p] = part_ml[(((size_t)h * 80 + base + p) * 2 + v) * 64 + row];
        M = fmaxf(M, ml[p].x);
    }
    float L = 0.f;
    float acc[32] = {};
    for (int p = 0; p < nsp; ++p) {
        float sc = __expf(ml[p].x - M);
        L += sc * ml[p].y;
        const __bf16* src =
            &part_O[((((size_t)h * 80 + base + p) * 2 + v) * 64 + row) * 64 + colh];
        for (int k = 0; k < 4; ++k) {
            bf16x8 o = *(const bf16x8*)&src[k * 8];
            for (int e = 0; e < 8; ++e) acc[k * 8 + e] += sc * (float)o[e];
        }
    }
    float inv = 1.f / L;
    __bf16* dst = &cat[(size_t)(qt * 64 + row) * 2048 + v * 1024 + h * 64 + colh];
    for (int k = 0; k < 4; ++k) {
        union { __bf16 hh[8]; float4 f4; } u;
        for (int e = 0; e < 8; ++e) u.hh[e] = (__bf16)(acc[k * 8 + e] * inv);
        *(float4*)&dst[k * 8] = u.f4;
    }
}

// ---------------- sigmoid-sum over strict upper tiles ----------------
__global__ void zero_acc_kernel(float* acc) { acc[0] = 0.f; }

__global__ __launch_bounds__(256) void sigmean_upper_kernel(
    const float* __restrict__ lm, float* __restrict__ acc)
{
    const int qt = blockIdx.x, h = blockIdx.y, rg = blockIdx.z;
    const int sc0 = (qt + 1) * 64;
    const int len4 = (T_SEQ - sc0) >> 2;
    float s = 0.f;
    for (int r = 0; r < 16; ++r) {
        const float* rowp = &lm[((size_t)h * T_SEQ + qt * 64 + rg * 16 + r) * T_SEQ + sc0];
        for (int c = threadIdx.x; c < len4; c += 256) {
            float4 a = *(const float4*)&rowp[c * 4];
            s += sigm(a.x) + sigm(a.y) + sigm(a.z) + sigm(a.w);
        }
    }
    for (int off = 1; off < 64; off <<= 1) s += __shfl_xor(s, off);
    if ((threadIdx.x & 63) == 0) atomicAdd(acc, s);
}

__global__ void write_sp_kernel(const float* __restrict__ acc, float* __restrict__ out)
{
    out[(size_t)T_SEQ * D_MODEL] = 0.0005f * acc[0] * (1.f / 67108864.f);
}

// ---------------- launch ----------------
extern "C" void kernel_launch(void* const* d_in, const int* in_sizes, int n_in,
                              void* d_out, int out_size, void* d_ws, size_t ws_size,
                              hipStream_t stream)
{
    const float* x      = (const float*)d_in[0];
    const float* W_qkv  = (const float*)d_in[2];
    const float* W_out  = (const float*)d_in[3];
    const float* lmask  = (const float*)d_in[4];
    const float* W_gate = (const float*)d_in[5];
    const float* b_gate = (const float*)d_in[6];
    const float* g1     = (const float*)d_in[7];
    const float* b1     = (const float*)d_in[8];
    const float* g2     = (const float*)d_in[9];
    const float* b2     = (const float*)d_in[10];
    const float* W_ff1  = (const float*)d_in[11];
    const float* b_ff1  = (const float*)d_in[12];
    const float* W_ff2  = (const float*)d_in[13];
    const float* b_ff2  = (const float*)d_in[14];
    float* out = (float*)d_out;

    char* ws = (char*)d_ws;
    size_t off = 0;
    auto alloc = [&](size_t bytes) {
        char* p = ws + off;
        off += (bytes + 255) & ~(size_t)255;
        return p;
    };
    __bf16* wq_b   = (__bf16*)alloc((size_t)3072 * 1024 * 2);
    __bf16* wout_b = (__bf16*)alloc((size_t)1024 * 1024 * 2);
    __bf16* wg_b   = (__bf16*)alloc((size_t)1024 * 2048 * 2);
    __bf16* wf1_b  = (__bf16*)alloc((size_t)4096 * 1024 * 2);
    __bf16* wf2_b  = (__bf16*)alloc((size_t)1024 * 4096 * 2);
    __bf16* xn_b   = (__bf16*)alloc((size_t)2048 * 1024 * 2);
    __bf16* qkv_b  = (__bf16*)alloc((size_t)2048 * 3072 * 2);
    __bf16* cat_b  = (__bf16*)alloc((size_t)2048 * 2048 * 2);
    __bf16* a1_b   = (__bf16*)alloc((size_t)2048 * 1024 * 2);
    float*  h_f    = (float*)alloc((size_t)2048 * 1024 * 4);
    __bf16* hn_b   = (__bf16*)alloc((size_t)2048 * 1024 * 2);
    __bf16* e_b    = (__bf16*)alloc((size_t)2048 * 4096 * 2);
    __bf16* part_O = (__bf16*)alloc((size_t)16 * 80 * 2 * 64 * 64 * 2);
    float2* part_ml= (float2*)alloc((size_t)16 * 80 * 2 * 64 * 8);
    float*  acc    = (float*)alloc(256);

    zero_acc_kernel<<<1, 1, 0, stream>>>(acc);

    cast_bf16_kernel<<<(3072 * 1024 / 8 + 255) / 256, 256, 0, stream>>>(W_qkv, wq_b, 3072 * 1024 / 8);
    cast_bf16_kernel<<<(1024 * 1024 / 8 + 255) / 256, 256, 0, stream>>>(W_out, wout_b, 1024 * 1024 / 8);
    cast_bf16_kernel<<<(1024 * 2048 / 8 + 255) / 256, 256, 0, stream>>>(W_gate, wg_b, 1024 * 2048 / 8);
    cast_bf16_kernel<<<(4096 * 1024 / 8 + 255) / 256, 256, 0, stream>>>(W_ff1, wf1_b, 4096 * 1024 / 8);
    cast_bf16_kernel<<<(1024 * 4096 / 8 + 255) / 256, 256, 0, stream>>>(W_ff2, wf2_b, 1024 * 4096 / 8);

    ln_kernel<<<2048, 256, 0, stream>>>(x, g1, b1, xn_b);
    gemm_nt<128, 0><<<dim3(16, 24), 256, 0, stream>>>(xn_b, wq_b, nullptr, nullptr, qkv_b, nullptr, 2048, 3072, 1024);
    attn_split_kernel<<<dim3(80, 16), 256, 0, stream>>>(qkv_b, lmask, part_O, part_ml, acc);
    attn_combine_kernel<<<dim3(32, 16), 256, 0, stream>>>(part_O, part_ml, cat_b);
    sigmean_upper_kernel<<<dim3(32, 16, 4), 256, 0, stream>>>(lmask, acc);

    gemm_nt<64, 0><<<dim3(32, 8), 256, 0, stream>>>(cat_b, wg_b, b_gate, nullptr, a1_b, nullptr, 2048, 1024, 2048);
    gemm_nt<64, 2><<<dim3(32, 8), 256, 0, stream>>>(a1_b, wout_b, nullptr, x, nullptr, h_f, 2048, 1024, 1024);
    ln_kernel<<<2048, 256, 0, stream>>>(h_f, g2, b2, hn_b);
    gemm_nt<128, 1><<<dim3(16, 32), 256, 0, stream>>>(hn_b, wf1_b, b_ff1, nullptr, e_b, nullptr, 2048, 4096, 1024);
    gemm_nt<64, 2><<<dim3(32, 8), 256, 0, stream>>>(e_b, wf2_b, b_ff2, h_f, nullptr, out, 2048, 1024, 4096);

    write_sp_kernel<<<1, 1, 0, stream>>>(acc, out);

    (void)in_sizes; (void)n_in; (void)out_size; (void)ws_size;
}